// Round 1
// baseline (104603.259 us; speedup 1.0000x reference)
//
#include <hip/hip_runtime.h>
#include <hip/hip_cooperative_groups.h>

namespace cg = cooperative_groups;

// ---------------- problem dims ----------------
#define BATCH   64
#define SEQ     512
#define HID     512
#define G4      2048      // 4*HID gate rows
#define DPRIM   64
#define DAUX    32
#define DIN     96
#define CT      32        // timesteps per chunk
#define NCHUNK  16        // SEQ/CT

// ---------------- rec partition ----------------
// 256 WGs = 4 batch-groups x 64 unit-groups. WG owns NB=16 batches, NU=8 units
// (=32 gate rows). Weights slice LDS-resident; h broadcast via global + grid sync.
#define NB 16
#define NU 8
#define NR 32
#define KPAD 68           // padded stride of one 64-wide k-chunk
#define WST  544          // row stride for W/h LDS (= 8*KPAD)
#define XST  100          // row stride for x / W_ih0 LDS (96 + pad)
#define PST  18           // P[r][b] stride

// ---------------- ws layout (float offsets) ----------------
#define OFF_HBUF0 0
#define OFF_HBUF1 (OFF_HBUF0 + 2*BATCH*HID)
#define OFF_CBUF0 (OFF_HBUF1 + 2*BATCH*HID)
#define OFF_CBUF1 (OFF_CBUF0 + BATCH*HID)
#define OFF_STATE_END (OFF_CBUF1 + BATCH*HID)       // 196608 floats zeroed per call
#define OFF_WP    OFF_STATE_END                     // permuted W_ih1 [2048][512]
#define OFF_BIASP (OFF_WP + G4*HID)                 // permuted b_ih1+b_hh1 [2048]
#define OFF_WOT   (OFF_BIASP + G4)                  // W_out^T [512][128]
#define OFF_HIST  (OFF_WOT + HID*128)               // layer0 h chunk [64][CT][512]
#define OFF_XP    (OFF_HIST + BATCH*CT*HID)         // xproj1 chunk [64][CT][2048]
// total = OFF_XP + BATCH*CT*G4 = 6,555,648 floats = 26.2 MB

__device__ __forceinline__ float sigm(float x)  { return 1.f / (1.f + __expf(-x)); }
__device__ __forceinline__ float tanh_f(float x){ return 1.f - 2.f / (__expf(2.f * x) + 1.f); }

// =====================================================================
// prep: permute W_ih1 rows to rec1's (ug,gate,u) order; combine biases;
// transpose W_out. Runs every call (deterministic).
// =====================================================================
__global__ void prep_kernel(const float* __restrict__ Wih1, const float* __restrict__ bih1,
                            const float* __restrict__ bhh1, const float* __restrict__ Wout,
                            float* __restrict__ Wp, float* __restrict__ biasp,
                            float* __restrict__ Wot)
{
    int idx = blockIdx.x * 256 + threadIdx.x;          // 0..262143
    {
        int n = idx >> 7, fq = idx & 127;              // n = permuted row, fq = f4 col
        int ugg = n >> 5, gate = (n >> 3) & 3, u = n & 7;
        int grow = gate * HID + ugg * 8 + u;
        *(float4*)(Wp + (size_t)n * HID + fq * 4) =
            *(const float4*)(Wih1 + (size_t)grow * HID + fq * 4);
    }
    if (idx < G4) {
        int n = idx;
        int ugg = n >> 5, gate = (n >> 3) & 3, u = n & 7;
        int grow = gate * HID + ugg * 8 + u;
        biasp[n] = bih1[grow] + bhh1[grow];
    }
    if (idx < HID * 128) {                             // Wot[k][o] = Wout[o][k]
        int k = idx >> 7, o = idx & 127;
        Wot[idx] = Wout[(size_t)o * HID + k];
    }
}

// =====================================================================
// rec0: layer-0 LSTM, input projection fused (K=96). Cooperative.
// grid 256 x 512 threads. One chunk of CT steps per launch.
// =====================================================================
__global__ __launch_bounds__(512, 2)
void rec0_kernel(const float* __restrict__ prim, const float* __restrict__ aux,
                 const float* __restrict__ Wih0, const float* __restrict__ Whh0,
                 const float* __restrict__ bih0, const float* __restrict__ bhh0,
                 float* __restrict__ hbuf, float* __restrict__ cbuf,
                 float* __restrict__ hist, int chunk)
{
    __shared__ float Wh[NR * WST];    // 69632 B  recurrent weight slice
    __shared__ float Hs[NB * WST];    // 34816 B  staged h_prev
    __shared__ float Wx[NR * XST];    // 12800 B  input weight slice
    __shared__ float Xs[NB * XST];    //  6400 B  staged x (prim | aux)
    __shared__ float Ps[NR * PST];    //  2304 B  gate pre-activations
    __shared__ float Cs[NB * NU];     //   512 B  cell state
    __shared__ float Bsum[NR];

    const int tid = threadIdx.x;
    const int wg  = blockIdx.x;
    const int bg  = wg & 3;          // batch group (keeps a group on 2 XCDs)
    const int ug  = wg >> 2;         // unit group
    const int b0  = bg * NB;
    const int u0  = ug * NU;

    // ---- one-time (per chunk) loads ----
    for (int i = tid; i < NR * 128; i += 512) {        // W_hh slice, f4
        int rl = i >> 7, fq = i & 127;
        int gate = rl >> 3, u = rl & 7;
        float4 v = *(const float4*)(Whh0 + (size_t)(gate * HID + u0 + u) * HID + fq * 4);
        int k = fq * 4;
        *(float4*)(Wh + rl * WST + (k >> 6) * KPAD + (k & 63)) = v;
    }
    for (int i = tid; i < NR * 24; i += 512) {         // W_ih0 slice (96 = 24 f4)
        int rl = i / 24, fq = i % 24;
        int gate = rl >> 3, u = rl & 7;
        float4 v = *(const float4*)(Wih0 + (size_t)(gate * HID + u0 + u) * DIN + fq * 4);
        *(float4*)(Wx + rl * XST + fq * 4) = v;
    }
    if (tid < NR) {
        int gate = tid >> 3, u = tid & 7;
        int grow = gate * HID + u0 + u;
        Bsum[tid] = bih0[grow] + bhh0[grow];
    }
    for (int i = tid; i < NB * DAUX; i += 512) {       // aux is time-invariant
        int b = i >> 5, k = i & 31;
        Xs[b * XST + DPRIM + k] = aux[(size_t)(b0 + b) * DAUX + k];
    }
    for (int i = tid; i < NB * NU; i += 512) {         // cell state
        int b = i >> 3, u = i & 7;
        Cs[i] = cbuf[(size_t)(b0 + b) * HID + u0 + u];
    }

    const int rt = tid >> 6;          // 0..7  -> rows rt*4..+3 (wave id)
    const int bt = (tid >> 3) & 7;    // 0..7  -> batches bt*2, bt*2+1
    const int ks = tid & 7;           // 0..7  -> k-slice [ks*64, ks*64+64)

    cg::grid_group grid = cg::this_grid();
    __syncthreads();

    for (int tl = 0; tl < CT; ++tl) {
        const int t = chunk * CT + tl;
        const int p = t & 1;
        const float* hprev = hbuf + (size_t)(p ^ 1) * (BATCH * HID);

        // ---- stage h_prev, x(t); init P with bias ----
        for (int i = tid; i < NB * 128; i += 512) {
            int b = i >> 7, fq = i & 127;
            float4 v = *(const float4*)(hprev + (size_t)(b0 + b) * HID + fq * 4);
            int k = fq * 4;
            *(float4*)(Hs + b * WST + (k >> 6) * KPAD + (k & 63)) = v;
        }
        for (int i = tid; i < NB * 16; i += 512) {
            int b = i >> 4, fq = i & 15;
            float4 v = *(const float4*)(prim + ((size_t)(b0 + b) * SEQ + t) * DPRIM + fq * 4);
            *(float4*)(Xs + b * XST + fq * 4) = v;
        }
        {
            int r = tid >> 4, b = tid & 15;            // exactly 32x16
            Ps[r * PST + b] = Bsum[r];
        }
        __syncthreads();

        // ---- partial dots: rows rt*4..+3, batches bt*2..+1, k in [ks*64,+64) ----
        float acc[4][2];
#pragma unroll
        for (int i = 0; i < 4; ++i) { acc[i][0] = 0.f; acc[i][1] = 0.f; }
        {
            const float* wb = Wh + (rt * 4) * WST + ks * KPAD;
            const float* hb = Hs + (bt * 2) * WST + ks * KPAD;
#pragma unroll
            for (int kk = 0; kk < 64; kk += 4) {
                float4 h0 = *(const float4*)(hb + kk);
                float4 h1 = *(const float4*)(hb + WST + kk);
#pragma unroll
                for (int i = 0; i < 4; ++i) {
                    float4 wv = *(const float4*)(wb + i * WST + kk);
                    acc[i][0] += wv.x * h0.x + wv.y * h0.y + wv.z * h0.z + wv.w * h0.w;
                    acc[i][1] += wv.x * h1.x + wv.y * h1.y + wv.z * h1.z + wv.w * h1.w;
                }
            }
        }
        {   // fused input projection: k in [ks*12, ks*12+12)
            const float* wxb = Wx + (rt * 4) * XST;
            const float* xb  = Xs + (bt * 2) * XST;
#pragma unroll
            for (int kk2 = 0; kk2 < 12; ++kk2) {
                int kk = ks * 12 + kk2;
                float x0 = xb[kk], x1 = xb[XST + kk];
#pragma unroll
                for (int i = 0; i < 4; ++i) {
                    float wv = wxb[i * XST + kk];
                    acc[i][0] += wv * x0;
                    acc[i][1] += wv * x1;
                }
            }
        }
        // ---- reduce over ks (lane bits 0..2) ----
#pragma unroll
        for (int i = 0; i < 4; ++i)
#pragma unroll
            for (int j = 0; j < 2; ++j) {
                float v = acc[i][j];
                v += __shfl_xor(v, 1);
                v += __shfl_xor(v, 2);
                v += __shfl_xor(v, 4);
                acc[i][j] = v;
            }
        if (ks == 0) {
#pragma unroll
            for (int i = 0; i < 4; ++i)
#pragma unroll
                for (int j = 0; j < 2; ++j)
                    Ps[(rt * 4 + i) * PST + bt * 2 + j] += acc[i][j];
        }
        __syncthreads();

        // ---- activations + state update + h publish ----
        if (tid < 128) {
            int b = tid >> 3, u = tid & 7;
            float gi = Ps[(u)      * PST + b];
            float gf = Ps[(8  + u) * PST + b];
            float gg = Ps[(16 + u) * PST + b];
            float go = Ps[(24 + u) * PST + b];
            float si = sigm(gi), sf = sigm(gf), so = sigm(go);
            float tg = tanh_f(gg);
            float cNew = sf * Cs[b * NU + u] + si * tg;
            Cs[b * NU + u] = cNew;
            float hNew = so * tanh_f(cNew);
            size_t gb = (size_t)(b0 + b);
            hbuf[(size_t)p * (BATCH * HID) + gb * HID + u0 + u] = hNew;
            hist[(gb * CT + tl) * HID + u0 + u] = hNew;
        }
        __threadfence();     // release h to other XCDs
        grid.sync();
        __threadfence();     // acquire (invalidate stale L1/L2 before re-reading h)
    }
    for (int i = tid; i < NB * NU; i += 512) {
        int b = i >> 3, u = i & 7;
        cbuf[(size_t)(b0 + b) * HID + u0 + u] = Cs[i];
    }
}

// =====================================================================
// rec1: layer-1 LSTM; x-projection comes precomputed (permuted) from xp.
// =====================================================================
__global__ __launch_bounds__(512, 2)
void rec1_kernel(const float* __restrict__ xp, const float* __restrict__ Whh1,
                 float* __restrict__ hbuf, float* __restrict__ cbuf, int chunk)
{
    __shared__ float Wh[NR * WST];
    __shared__ float Hs[NB * WST];
    __shared__ float Ps[NR * PST];
    __shared__ float Cs[NB * NU];

    const int tid = threadIdx.x;
    const int wg  = blockIdx.x;
    const int bg  = wg & 3;
    const int ug  = wg >> 2;
    const int b0  = bg * NB;
    const int u0  = ug * NU;

    for (int i = tid; i < NR * 128; i += 512) {
        int rl = i >> 7, fq = i & 127;
        int gate = rl >> 3, u = rl & 7;
        float4 v = *(const float4*)(Whh1 + (size_t)(gate * HID + u0 + u) * HID + fq * 4);
        int k = fq * 4;
        *(float4*)(Wh + rl * WST + (k >> 6) * KPAD + (k & 63)) = v;
    }
    for (int i = tid; i < NB * NU; i += 512) {
        int b = i >> 3, u = i & 7;
        Cs[i] = cbuf[(size_t)(b0 + b) * HID + u0 + u];
    }

    const int rt = tid >> 6;
    const int bt = (tid >> 3) & 7;
    const int ks = tid & 7;

    cg::grid_group grid = cg::this_grid();
    __syncthreads();

    for (int tl = 0; tl < CT; ++tl) {
        const int t = chunk * CT + tl;
        const int p = t & 1;
        const float* hprev = hbuf + (size_t)(p ^ 1) * (BATCH * HID);

        for (int i = tid; i < NB * 128; i += 512) {
            int b = i >> 7, fq = i & 127;
            float4 v = *(const float4*)(hprev + (size_t)(b0 + b) * HID + fq * 4);
            int k = fq * 4;
            *(float4*)(Hs + b * WST + (k >> 6) * KPAD + (k & 63)) = v;
        }
        {   // P init = precomputed x-projection (+biases), permuted layout
            int b = tid >> 5, idx = tid & 31;          // exactly 16x32
            Ps[idx * PST + b] = xp[((size_t)(b0 + b) * CT + tl) * G4 + ug * 32 + idx];
        }
        __syncthreads();

        float acc[4][2];
#pragma unroll
        for (int i = 0; i < 4; ++i) { acc[i][0] = 0.f; acc[i][1] = 0.f; }
        {
            const float* wb = Wh + (rt * 4) * WST + ks * KPAD;
            const float* hb = Hs + (bt * 2) * WST + ks * KPAD;
#pragma unroll
            for (int kk = 0; kk < 64; kk += 4) {
                float4 h0 = *(const float4*)(hb + kk);
                float4 h1 = *(const float4*)(hb + WST + kk);
#pragma unroll
                for (int i = 0; i < 4; ++i) {
                    float4 wv = *(const float4*)(wb + i * WST + kk);
                    acc[i][0] += wv.x * h0.x + wv.y * h0.y + wv.z * h0.z + wv.w * h0.w;
                    acc[i][1] += wv.x * h1.x + wv.y * h1.y + wv.z * h1.z + wv.w * h1.w;
                }
            }
        }
#pragma unroll
        for (int i = 0; i < 4; ++i)
#pragma unroll
            for (int j = 0; j < 2; ++j) {
                float v = acc[i][j];
                v += __shfl_xor(v, 1);
                v += __shfl_xor(v, 2);
                v += __shfl_xor(v, 4);
                acc[i][j] = v;
            }
        if (ks == 0) {
#pragma unroll
            for (int i = 0; i < 4; ++i)
#pragma unroll
                for (int j = 0; j < 2; ++j)
                    Ps[(rt * 4 + i) * PST + bt * 2 + j] += acc[i][j];
        }
        __syncthreads();

        if (tid < 128) {
            int b = tid >> 3, u = tid & 7;
            float gi = Ps[(u)      * PST + b];
            float gf = Ps[(8  + u) * PST + b];
            float gg = Ps[(16 + u) * PST + b];
            float go = Ps[(24 + u) * PST + b];
            float si = sigm(gi), sf = sigm(gf), so = sigm(go);
            float tg = tanh_f(gg);
            float cNew = sf * Cs[b * NU + u] + si * tg;
            Cs[b * NU + u] = cNew;
            float hNew = so * tanh_f(cNew);
            hbuf[(size_t)p * (BATCH * HID) + (size_t)(b0 + b) * HID + u0 + u] = hNew;
        }
        __threadfence();
        grid.sync();
        __threadfence();
    }
    for (int i = tid; i < NB * NU; i += 512) {
        int b = i >> 3, u = i & 7;
        cbuf[(size_t)(b0 + b) * HID + u0 + u] = Cs[i];
    }
}

// =====================================================================
// xp1 GEMM: C[m][n] = sum_k A[m][k]*Bp[n][k] + biasp[n]
// A = hist chunk [2048][512], Bp = permuted W_ih1 [2048][512], C = xp chunk.
// 128x128 tile, 256 thr, 8x8 micro, 8x8 wave shape (conflict-free LDS reads).
// =====================================================================
__global__ __launch_bounds__(256, 2)
void gemm_xp1(const float* __restrict__ A, const float* __restrict__ Bp,
              const float* __restrict__ biasp, float* __restrict__ C)
{
    __shared__ float As[8][132];
    __shared__ float Bs[8][132];
    const int tid = threadIdx.x;
    const int m0 = blockIdx.x * 128;
    const int n0 = blockIdx.y * 128;
    const int tx = (tid & 7) | ((tid >> 3) & 8);   // 8x8 within a wave
    const int ty = ((tid >> 3) & 7) | ((tid >> 4) & 8);
    const int lrow = tid >> 1;
    const int lkq  = (tid & 1) * 4;

    float acc[8][8];
#pragma unroll
    for (int i = 0; i < 8; ++i)
#pragma unroll
        for (int j = 0; j < 8; ++j) acc[i][j] = 0.f;

    const float* Aptr = A  + (size_t)(m0 + lrow) * HID + lkq;
    const float* Bptr = Bp + (size_t)(n0 + lrow) * HID + lkq;

    for (int kt = 0; kt < HID; kt += 8) {
        float4 av = *(const float4*)(Aptr + kt);
        float4 bv = *(const float4*)(Bptr + kt);
        __syncthreads();
        As[lkq + 0][lrow] = av.x; As[lkq + 1][lrow] = av.y;
        As[lkq + 2][lrow] = av.z; As[lkq + 3][lrow] = av.w;
        Bs[lkq + 0][lrow] = bv.x; Bs[lkq + 1][lrow] = bv.y;
        Bs[lkq + 2][lrow] = bv.z; Bs[lkq + 3][lrow] = bv.w;
        __syncthreads();
#pragma unroll
        for (int k = 0; k < 8; ++k) {
            float4 a0 = *(const float4*)(&As[k][ty * 8]);
            float4 a1 = *(const float4*)(&As[k][ty * 8 + 4]);
            float4 b0 = *(const float4*)(&Bs[k][tx * 8]);
            float4 b1 = *(const float4*)(&Bs[k][tx * 8 + 4]);
            float am[8] = {a0.x, a0.y, a0.z, a0.w, a1.x, a1.y, a1.z, a1.w};
            float bn[8] = {b0.x, b0.y, b0.z, b0.w, b1.x, b1.y, b1.z, b1.w};
#pragma unroll
            for (int i = 0; i < 8; ++i)
#pragma unroll
                for (int j = 0; j < 8; ++j) acc[i][j] += am[i] * bn[j];
        }
    }
#pragma unroll
    for (int i = 0; i < 8; ++i) {
        int m = m0 + ty * 8 + i;
        float* crow = C + (size_t)m * G4 + n0 + tx * 8;
#pragma unroll
        for (int j = 0; j < 8; ++j) crow[j] = acc[i][j] + biasp[n0 + tx * 8 + j];
    }
}

// =====================================================================
// output projection: out[b][o] = h_last[b]·Wot[:,o] + b_out[o]
// =====================================================================
__global__ void outproj_kernel(const float* __restrict__ hlast, const float* __restrict__ Wot,
                               const float* __restrict__ bout, float* __restrict__ out)
{
    __shared__ float hs[HID];
    int b = blockIdx.x;
    for (int i = threadIdx.x; i < HID; i += 128) hs[i] = hlast[(size_t)b * HID + i];
    __syncthreads();
    int o = threadIdx.x;
    float acc = bout[o];
#pragma unroll 8
    for (int k = 0; k < HID; ++k) acc = fmaf(hs[k], Wot[k * 128 + o], acc);
    out[b * 128 + o] = acc;
}

// =====================================================================
extern "C" void kernel_launch(void* const* d_in, const int* in_sizes, int n_in,
                              void* d_out, int out_size, void* d_ws, size_t ws_size,
                              hipStream_t stream)
{
    const float* prim = (const float*)d_in[0];
    const float* aux  = (const float*)d_in[1];
    const float* Wih0 = (const float*)d_in[2];
    const float* Whh0 = (const float*)d_in[3];
    const float* bih0 = (const float*)d_in[4];
    const float* bhh0 = (const float*)d_in[5];
    const float* Wih1 = (const float*)d_in[6];
    const float* Whh1 = (const float*)d_in[7];
    const float* bih1 = (const float*)d_in[8];
    const float* bhh1 = (const float*)d_in[9];
    const float* Wout = (const float*)d_in[10];
    const float* bout = (const float*)d_in[11];
    float* out = (float*)d_out;
    float* ws  = (float*)d_ws;

    float* hbuf0 = ws + OFF_HBUF0;
    float* hbuf1 = ws + OFF_HBUF1;
    float* cbuf0 = ws + OFF_CBUF0;
    float* cbuf1 = ws + OFF_CBUF1;
    float* Wp    = ws + OFF_WP;
    float* biasp = ws + OFF_BIASP;
    float* Wot   = ws + OFF_WOT;
    float* hist  = ws + OFF_HIST;
    float* xp    = ws + OFF_XP;

    // zero h/c state (graph-replay determinism)
    hipMemsetAsync(ws, 0, (size_t)OFF_STATE_END * sizeof(float), stream);
    prep_kernel<<<1024, 256, 0, stream>>>(Wih1, bih1, bhh1, Wout, Wp, biasp, Wot);

    for (int c = 0; c < NCHUNK; ++c) {
        int cc = c;
        void* a0[] = {(void*)&prim, (void*)&aux, (void*)&Wih0, (void*)&Whh0,
                      (void*)&bih0, (void*)&bhh0, (void*)&hbuf0, (void*)&cbuf0,
                      (void*)&hist, (void*)&cc};
        hipLaunchCooperativeKernel((void*)rec0_kernel, dim3(256), dim3(512), a0, 0, stream);

        gemm_xp1<<<dim3((CT * BATCH) / 128, G4 / 128), 256, 0, stream>>>(hist, Wp, biasp, xp);

        void* a1[] = {(void*)&xp, (void*)&Whh1, (void*)&hbuf1, (void*)&cbuf1, (void*)&cc};
        hipLaunchCooperativeKernel((void*)rec1_kernel, dim3(256), dim3(512), a1, 0, stream);
    }
    // t=511 has parity 1 -> second half of hbuf1
    outproj_kernel<<<64, 128, 0, stream>>>(hbuf1 + BATCH * HID, Wot, bout, out);
}

// Round 2
// 11259.407 us; speedup vs baseline: 9.2903x; 9.2903x over previous
//
#include <hip/hip_runtime.h>

// ---------------- problem dims ----------------
#define BATCH   64
#define SEQ     512
#define HID     512
#define G4      2048      // 4*HID gate rows
#define DPRIM   64
#define DAUX    32
#define DIN     96
#define CT      32        // timesteps per chunk
#define NCHUNK  16        // SEQ/CT

// ---------------- rec partition ----------------
// 256 WGs = 4 batch-groups x 64 unit-groups. WG owns NB=16 batches, NU=8 units
// (=32 gate rows). Weights LDS-resident; h exchanged via coherent (agent-scope
// relaxed atomic) loads/stores through the memory-side cache — NO threadfence,
// NO grid.sync. Each batch-group has its own 64-WG spin barrier.
#define NB 16
#define NU 8
#define NR 32
#define KPAD 68           // padded stride of one 64-wide k-chunk
#define WST  544          // row stride for W/h LDS (= 8*KPAD)
#define XST  100          // row stride for x / W_ih0 LDS (96 + pad)
#define PST  18           // P[r][b] stride

// ---------------- ws layout (float offsets) ----------------
#define OFF_HBUF0 0
#define OFF_HBUF1 (OFF_HBUF0 + 2*BATCH*HID)
#define OFF_CBUF0 (OFF_HBUF1 + 2*BATCH*HID)
#define OFF_CBUF1 (OFF_CBUF0 + BATCH*HID)
#define OFF_BAR   (OFF_CBUF1 + BATCH*HID)           // 2 layers x 4 bg x 64-int spacing
#define OFF_STATE_END (OFF_BAR + 512)               // zeroed per call
#define OFF_WP    OFF_STATE_END                     // permuted W_ih1 [2048][512]
#define OFF_BIASP (OFF_WP + G4*HID)                 // permuted b_ih1+b_hh1 [2048]
#define OFF_WOT   (OFF_BIASP + G4)                  // W_out^T [512][128]
#define OFF_HIST  (OFF_WOT + HID*128)               // layer0 h chunk [64][CT][512]
#define OFF_XP    (OFF_HIST + BATCH*CT*HID)         // xproj1 chunk [64][CT][2048]
// total = OFF_XP + BATCH*CT*G4 floats ~= 26.2 MB

__device__ __forceinline__ float sigm(float x)  { return 1.f / (1.f + __expf(-x)); }
__device__ __forceinline__ float tanh_f(float x){ return 1.f - 2.f / (__expf(2.f * x) + 1.f); }

// coherent (cross-XCD) scalar access via agent-scope relaxed atomics:
// compiles to global_load/store with sc1 (bypasses non-coherent XCD L2).
__device__ __forceinline__ float ld_coh(const float* p) {
    return __hip_atomic_load(p, __ATOMIC_RELAXED, __HIP_MEMORY_SCOPE_AGENT);
}
__device__ __forceinline__ void st_coh(float* p, float v) {
    __hip_atomic_store(p, v, __ATOMIC_RELAXED, __HIP_MEMORY_SCOPE_AGENT);
}

// 64-WG spin barrier for one batch-group. Monotonic target; bar zeroed per call.
// Caller must __syncthreads() BEFORE (drains vmcnt -> h stores complete) and
// AFTER (broadcast release to all waves).
__device__ __forceinline__ void group_barrier(int* bar, int target, int tid) {
    if (tid == 0) {
        __hip_atomic_fetch_add(bar, 1, __ATOMIC_RELAXED, __HIP_MEMORY_SCOPE_AGENT);
        while (__hip_atomic_load(bar, __ATOMIC_RELAXED, __HIP_MEMORY_SCOPE_AGENT) < target) {}
    }
}

// =====================================================================
// prep: permute W_ih1 rows to rec1's (ug,gate,u) order; combine biases;
// transpose W_out.
// =====================================================================
__global__ void prep_kernel(const float* __restrict__ Wih1, const float* __restrict__ bih1,
                            const float* __restrict__ bhh1, const float* __restrict__ Wout,
                            float* __restrict__ Wp, float* __restrict__ biasp,
                            float* __restrict__ Wot)
{
    int idx = blockIdx.x * 256 + threadIdx.x;          // 0..262143
    {
        int n = idx >> 7, fq = idx & 127;              // n = permuted row, fq = f4 col
        int ugg = n >> 5, gate = (n >> 3) & 3, u = n & 7;
        int grow = gate * HID + ugg * 8 + u;
        *(float4*)(Wp + (size_t)n * HID + fq * 4) =
            *(const float4*)(Wih1 + (size_t)grow * HID + fq * 4);
    }
    if (idx < G4) {
        int n = idx;
        int ugg = n >> 5, gate = (n >> 3) & 3, u = n & 7;
        int grow = gate * HID + ugg * 8 + u;
        biasp[n] = bih1[grow] + bhh1[grow];
    }
    if (idx < HID * 128) {                             // Wot[k][o] = Wout[o][k]
        int k = idx >> 7, o = idx & 127;
        Wot[idx] = Wout[(size_t)o * HID + k];
    }
}

// =====================================================================
// rec0: layer-0 LSTM, input projection fused (K=96). Cooperative (residency).
// =====================================================================
__global__ __launch_bounds__(512, 2)
void rec0_kernel(const float* __restrict__ prim, const float* __restrict__ aux,
                 const float* __restrict__ Wih0, const float* __restrict__ Whh0,
                 const float* __restrict__ bih0, const float* __restrict__ bhh0,
                 float* __restrict__ hbuf, float* __restrict__ cbuf,
                 float* __restrict__ hist, int* __restrict__ bar, int chunk)
{
    __shared__ float Wh[NR * WST];
    __shared__ float Hs[NB * WST];
    __shared__ float Wx[NR * XST];
    __shared__ float Xs[NB * XST];
    __shared__ float Ps[NR * PST];
    __shared__ float Cs[NB * NU];
    __shared__ float Bsum[NR];

    const int tid = threadIdx.x;
    const int wg  = blockIdx.x;
    const int bg  = wg & 3;
    const int ug  = wg >> 2;
    const int b0  = bg * NB;
    const int u0  = ug * NU;
    int* mybar = bar + bg * 64;          // 256B apart per batch-group

    for (int i = tid; i < NR * 128; i += 512) {        // W_hh slice
        int rl = i >> 7, fq = i & 127;
        int gate = rl >> 3, u = rl & 7;
        float4 v = *(const float4*)(Whh0 + (size_t)(gate * HID + u0 + u) * HID + fq * 4);
        int k = fq * 4;
        *(float4*)(Wh + rl * WST + (k >> 6) * KPAD + (k & 63)) = v;
    }
    for (int i = tid; i < NR * 24; i += 512) {         // W_ih0 slice
        int rl = i / 24, fq = i % 24;
        int gate = rl >> 3, u = rl & 7;
        float4 v = *(const float4*)(Wih0 + (size_t)(gate * HID + u0 + u) * DIN + fq * 4);
        *(float4*)(Wx + rl * XST + fq * 4) = v;
    }
    if (tid < NR) {
        int gate = tid >> 3, u = tid & 7;
        int grow = gate * HID + u0 + u;
        Bsum[tid] = bih0[grow] + bhh0[grow];
    }
    for (int i = tid; i < NB * DAUX; i += 512) {
        int b = i >> 5, k = i & 31;
        Xs[b * XST + DPRIM + k] = aux[(size_t)(b0 + b) * DAUX + k];
    }
    for (int i = tid; i < NB * NU; i += 512) {
        int b = i >> 3, u = i & 7;
        Cs[i] = cbuf[(size_t)(b0 + b) * HID + u0 + u];
    }

    const int rt = tid >> 6;
    const int bt = (tid >> 3) & 7;
    const int ks = tid & 7;
    __syncthreads();

    for (int tl = 0; tl < CT; ++tl) {
        const int t = chunk * CT + tl;
        const int p = t & 1;
        const float* hprev = hbuf + (size_t)(p ^ 1) * (BATCH * HID);

        // ---- stage h_prev (coherent scalar loads), x(t); init P ----
#pragma unroll
        for (int ii = 0; ii < 16; ++ii) {
            int i = tid + ii * 512;
            int b = i >> 9, k = i & 511;
            float v = ld_coh(hprev + (size_t)(b0 + b) * HID + k);
            Hs[b * WST + (k >> 6) * KPAD + (k & 63)] = v;
        }
        for (int i = tid; i < NB * 16; i += 512) {
            int b = i >> 4, fq = i & 15;
            float4 v = *(const float4*)(prim + ((size_t)(b0 + b) * SEQ + t) * DPRIM + fq * 4);
            *(float4*)(Xs + b * XST + fq * 4) = v;
        }
        {
            int r = tid >> 4, b = tid & 15;
            Ps[r * PST + b] = Bsum[r];
        }
        __syncthreads();

        // ---- partial dots ----
        float acc[4][2];
#pragma unroll
        for (int i = 0; i < 4; ++i) { acc[i][0] = 0.f; acc[i][1] = 0.f; }
        {
            const float* wb = Wh + (rt * 4) * WST + ks * KPAD;
            const float* hb = Hs + (bt * 2) * WST + ks * KPAD;
#pragma unroll
            for (int kk = 0; kk < 64; kk += 4) {
                float4 h0 = *(const float4*)(hb + kk);
                float4 h1 = *(const float4*)(hb + WST + kk);
#pragma unroll
                for (int i = 0; i < 4; ++i) {
                    float4 wv = *(const float4*)(wb + i * WST + kk);
                    acc[i][0] += wv.x * h0.x + wv.y * h0.y + wv.z * h0.z + wv.w * h0.w;
                    acc[i][1] += wv.x * h1.x + wv.y * h1.y + wv.z * h1.z + wv.w * h1.w;
                }
            }
        }
        {
            const float* wxb = Wx + (rt * 4) * XST;
            const float* xb  = Xs + (bt * 2) * XST;
#pragma unroll
            for (int kk2 = 0; kk2 < 12; ++kk2) {
                int kk = ks * 12 + kk2;
                float x0 = xb[kk], x1 = xb[XST + kk];
#pragma unroll
                for (int i = 0; i < 4; ++i) {
                    float wv = wxb[i * XST + kk];
                    acc[i][0] += wv * x0;
                    acc[i][1] += wv * x1;
                }
            }
        }
#pragma unroll
        for (int i = 0; i < 4; ++i)
#pragma unroll
            for (int j = 0; j < 2; ++j) {
                float v = acc[i][j];
                v += __shfl_xor(v, 1);
                v += __shfl_xor(v, 2);
                v += __shfl_xor(v, 4);
                acc[i][j] = v;
            }
        if (ks == 0) {
#pragma unroll
            for (int i = 0; i < 4; ++i)
#pragma unroll
                for (int j = 0; j < 2; ++j)
                    Ps[(rt * 4 + i) * PST + bt * 2 + j] += acc[i][j];
        }
        __syncthreads();

        // ---- activations + state update + coherent h publish ----
        if (tid < 128) {
            int b = tid >> 3, u = tid & 7;
            float gi = Ps[(u)      * PST + b];
            float gf = Ps[(8  + u) * PST + b];
            float gg = Ps[(16 + u) * PST + b];
            float go = Ps[(24 + u) * PST + b];
            float si = sigm(gi), sf = sigm(gf), so = sigm(go);
            float tg = tanh_f(gg);
            float cNew = sf * Cs[b * NU + u] + si * tg;
            Cs[b * NU + u] = cNew;
            float hNew = so * tanh_f(cNew);
            size_t gb = (size_t)(b0 + b);
            st_coh(hbuf + (size_t)p * (BATCH * HID) + gb * HID + u0 + u, hNew);
            hist[(gb * CT + tl) * HID + u0 + u] = hNew;
        }
        __syncthreads();                         // drains vmcnt: publishes complete
        group_barrier(mybar, 64 * (chunk * CT + tl + 1), tid);
        __syncthreads();
    }
    for (int i = tid; i < NB * NU; i += 512) {
        int b = i >> 3, u = i & 7;
        cbuf[(size_t)(b0 + b) * HID + u0 + u] = Cs[i];
    }
}

// =====================================================================
// rec1: layer-1 LSTM; x-projection precomputed (permuted) in xp.
// =====================================================================
__global__ __launch_bounds__(512, 2)
void rec1_kernel(const float* __restrict__ xp, const float* __restrict__ Whh1,
                 float* __restrict__ hbuf, float* __restrict__ cbuf,
                 int* __restrict__ bar, int chunk)
{
    __shared__ float Wh[NR * WST];
    __shared__ float Hs[NB * WST];
    __shared__ float Ps[NR * PST];
    __shared__ float Cs[NB * NU];

    const int tid = threadIdx.x;
    const int wg  = blockIdx.x;
    const int bg  = wg & 3;
    const int ug  = wg >> 2;
    const int b0  = bg * NB;
    const int u0  = ug * NU;
    int* mybar = bar + bg * 64;

    for (int i = tid; i < NR * 128; i += 512) {
        int rl = i >> 7, fq = i & 127;
        int gate = rl >> 3, u = rl & 7;
        float4 v = *(const float4*)(Whh1 + (size_t)(gate * HID + u0 + u) * HID + fq * 4);
        int k = fq * 4;
        *(float4*)(Wh + rl * WST + (k >> 6) * KPAD + (k & 63)) = v;
    }
    for (int i = tid; i < NB * NU; i += 512) {
        int b = i >> 3, u = i & 7;
        Cs[i] = cbuf[(size_t)(b0 + b) * HID + u0 + u];
    }

    const int rt = tid >> 6;
    const int bt = (tid >> 3) & 7;
    const int ks = tid & 7;
    __syncthreads();

    for (int tl = 0; tl < CT; ++tl) {
        const int t = chunk * CT + tl;
        const int p = t & 1;
        const float* hprev = hbuf + (size_t)(p ^ 1) * (BATCH * HID);

#pragma unroll
        for (int ii = 0; ii < 16; ++ii) {
            int i = tid + ii * 512;
            int b = i >> 9, k = i & 511;
            float v = ld_coh(hprev + (size_t)(b0 + b) * HID + k);
            Hs[b * WST + (k >> 6) * KPAD + (k & 63)] = v;
        }
        {
            int b = tid >> 5, idx = tid & 31;
            Ps[idx * PST + b] = xp[((size_t)(b0 + b) * CT + tl) * G4 + ug * 32 + idx];
        }
        __syncthreads();

        float acc[4][2];
#pragma unroll
        for (int i = 0; i < 4; ++i) { acc[i][0] = 0.f; acc[i][1] = 0.f; }
        {
            const float* wb = Wh + (rt * 4) * WST + ks * KPAD;
            const float* hb = Hs + (bt * 2) * WST + ks * KPAD;
#pragma unroll
            for (int kk = 0; kk < 64; kk += 4) {
                float4 h0 = *(const float4*)(hb + kk);
                float4 h1 = *(const float4*)(hb + WST + kk);
#pragma unroll
                for (int i = 0; i < 4; ++i) {
                    float4 wv = *(const float4*)(wb + i * WST + kk);
                    acc[i][0] += wv.x * h0.x + wv.y * h0.y + wv.z * h0.z + wv.w * h0.w;
                    acc[i][1] += wv.x * h1.x + wv.y * h1.y + wv.z * h1.z + wv.w * h1.w;
                }
            }
        }
#pragma unroll
        for (int i = 0; i < 4; ++i)
#pragma unroll
            for (int j = 0; j < 2; ++j) {
                float v = acc[i][j];
                v += __shfl_xor(v, 1);
                v += __shfl_xor(v, 2);
                v += __shfl_xor(v, 4);
                acc[i][j] = v;
            }
        if (ks == 0) {
#pragma unroll
            for (int i = 0; i < 4; ++i)
#pragma unroll
                for (int j = 0; j < 2; ++j)
                    Ps[(rt * 4 + i) * PST + bt * 2 + j] += acc[i][j];
        }
        __syncthreads();

        if (tid < 128) {
            int b = tid >> 3, u = tid & 7;
            float gi = Ps[(u)      * PST + b];
            float gf = Ps[(8  + u) * PST + b];
            float gg = Ps[(16 + u) * PST + b];
            float go = Ps[(24 + u) * PST + b];
            float si = sigm(gi), sf = sigm(gf), so = sigm(go);
            float tg = tanh_f(gg);
            float cNew = sf * Cs[b * NU + u] + si * tg;
            Cs[b * NU + u] = cNew;
            float hNew = so * tanh_f(cNew);
            st_coh(hbuf + (size_t)p * (BATCH * HID) + (size_t)(b0 + b) * HID + u0 + u, hNew);
        }
        __syncthreads();
        group_barrier(mybar, 64 * (chunk * CT + tl + 1), tid);
        __syncthreads();
    }
    for (int i = tid; i < NB * NU; i += 512) {
        int b = i >> 3, u = i & 7;
        cbuf[(size_t)(b0 + b) * HID + u0 + u] = Cs[i];
    }
}

// =====================================================================
// xp1 GEMM: C[m][n] = sum_k A[m][k]*Bp[n][k] + biasp[n]
// 64x64 tile, 256 thr, 4x4 micro, grid 32x32 = 1024 WGs (4/CU).
// =====================================================================
__global__ __launch_bounds__(256)
void gemm_xp1(const float* __restrict__ A, const float* __restrict__ Bp,
              const float* __restrict__ biasp, float* __restrict__ C)
{
    __shared__ float As[16][68];
    __shared__ float Bs[16][68];
    const int tid = threadIdx.x;
    const int m0 = blockIdx.x * 64;
    const int n0 = blockIdx.y * 64;
    const int tx = tid & 15;            // n sub-tile
    const int ty = tid >> 4;            // m sub-tile
    const int lrow = tid >> 2;          // 0..63 (k-major load: coalesced)
    const int lk   = (tid & 3) * 4;     // 0,4,8,12

    float acc[4][4];
#pragma unroll
    for (int i = 0; i < 4; ++i)
#pragma unroll
        for (int j = 0; j < 4; ++j) acc[i][j] = 0.f;

    const float* Aptr = A  + (size_t)(m0 + lrow) * HID + lk;
    const float* Bptr = Bp + (size_t)(n0 + lrow) * HID + lk;

    for (int kt = 0; kt < HID; kt += 16) {
        float4 av = *(const float4*)(Aptr + kt);
        float4 bv = *(const float4*)(Bptr + kt);
        __syncthreads();
        As[lk + 0][lrow] = av.x; As[lk + 1][lrow] = av.y;
        As[lk + 2][lrow] = av.z; As[lk + 3][lrow] = av.w;
        Bs[lk + 0][lrow] = bv.x; Bs[lk + 1][lrow] = bv.y;
        Bs[lk + 2][lrow] = bv.z; Bs[lk + 3][lrow] = bv.w;
        __syncthreads();
#pragma unroll
        for (int k = 0; k < 16; ++k) {
            float4 a = *(const float4*)(&As[k][ty * 4]);
            float4 b = *(const float4*)(&Bs[k][tx * 4]);
            float am[4] = {a.x, a.y, a.z, a.w};
            float bn[4] = {b.x, b.y, b.z, b.w};
#pragma unroll
            for (int i = 0; i < 4; ++i)
#pragma unroll
                for (int j = 0; j < 4; ++j) acc[i][j] += am[i] * bn[j];
        }
    }
    float4 bias = *(const float4*)(biasp + n0 + tx * 4);
#pragma unroll
    for (int i = 0; i < 4; ++i) {
        float4 o;
        o.x = acc[i][0] + bias.x; o.y = acc[i][1] + bias.y;
        o.z = acc[i][2] + bias.z; o.w = acc[i][3] + bias.w;
        *(float4*)(C + (size_t)(m0 + ty * 4 + i) * G4 + n0 + tx * 4) = o;
    }
}

// =====================================================================
// output projection
// =====================================================================
__global__ void outproj_kernel(const float* __restrict__ hlast, const float* __restrict__ Wot,
                               const float* __restrict__ bout, float* __restrict__ out)
{
    __shared__ float hs[HID];
    int b = blockIdx.x;
    for (int i = threadIdx.x; i < HID; i += 128) hs[i] = hlast[(size_t)b * HID + i];
    __syncthreads();
    int o = threadIdx.x;
    float acc = bout[o];
#pragma unroll 8
    for (int k = 0; k < HID; ++k) acc = fmaf(hs[k], Wot[k * 128 + o], acc);
    out[b * 128 + o] = acc;
}

// =====================================================================
extern "C" void kernel_launch(void* const* d_in, const int* in_sizes, int n_in,
                              void* d_out, int out_size, void* d_ws, size_t ws_size,
                              hipStream_t stream)
{
    const float* prim = (const float*)d_in[0];
    const float* aux  = (const float*)d_in[1];
    const float* Wih0 = (const float*)d_in[2];
    const float* Whh0 = (const float*)d_in[3];
    const float* bih0 = (const float*)d_in[4];
    const float* bhh0 = (const float*)d_in[5];
    const float* Wih1 = (const float*)d_in[6];
    const float* Whh1 = (const float*)d_in[7];
    const float* bih1 = (const float*)d_in[8];
    const float* bhh1 = (const float*)d_in[9];
    const float* Wout = (const float*)d_in[10];
    const float* bout = (const float*)d_in[11];
    float* out = (float*)d_out;
    float* ws  = (float*)d_ws;

    float* hbuf0 = ws + OFF_HBUF0;
    float* hbuf1 = ws + OFF_HBUF1;
    float* cbuf0 = ws + OFF_CBUF0;
    float* cbuf1 = ws + OFF_CBUF1;
    int*   bar0  = (int*)(ws + OFF_BAR);
    int*   bar1  = (int*)(ws + OFF_BAR + 256);
    float* Wp    = ws + OFF_WP;
    float* biasp = ws + OFF_BIASP;
    float* Wot   = ws + OFF_WOT;
    float* hist  = ws + OFF_HIST;
    float* xp    = ws + OFF_XP;

    hipMemsetAsync(ws, 0, (size_t)OFF_STATE_END * sizeof(float), stream);
    prep_kernel<<<1024, 256, 0, stream>>>(Wih1, bih1, bhh1, Wout, Wp, biasp, Wot);

    for (int c = 0; c < NCHUNK; ++c) {
        int cc = c;
        void* a0[] = {(void*)&prim, (void*)&aux, (void*)&Wih0, (void*)&Whh0,
                      (void*)&bih0, (void*)&bhh0, (void*)&hbuf0, (void*)&cbuf0,
                      (void*)&hist, (void*)&bar0, (void*)&cc};
        hipLaunchCooperativeKernel((void*)rec0_kernel, dim3(256), dim3(512), a0, 0, stream);

        gemm_xp1<<<dim3(32, 32), 256, 0, stream>>>(hist, Wp, biasp, xp);

        void* a1[] = {(void*)&xp, (void*)&Whh1, (void*)&hbuf1, (void*)&cbuf1,
                      (void*)&bar1, (void*)&cc};
        hipLaunchCooperativeKernel((void*)rec1_kernel, dim3(256), dim3(512), a1, 0, stream);
    }
    outproj_kernel<<<64, 128, 0, stream>>>(hbuf1 + BATCH * HID, Wot, bout, out);
}

// Round 3
// 6401.797 us; speedup vs baseline: 16.3397x; 1.7588x over previous
//
#include <hip/hip_runtime.h>

// ---------------- problem dims ----------------
#define BATCH 64
#define SEQ   512
#define HID   512
#define DPRIM 64
#define DAUX  32
#define DIN   96
#define CT    32
#define NCHUNK 16

// ---------------- rec partition ----------------
// 256 WGs = 4 batch-groups x 64 unit-groups; WG owns NB=16 batches, 32 gate rows.
// Weights LDS-resident as bf16 hi/lo pairs; compute = mfma_f32_16x16x32_bf16
// (bf16x3: hi*hi + hi*lo + lo*hi => fp32-grade precision).
// h exchanged via agent-scope (sc1/MALL) loads/stores; per-bg slot barrier.
#define NB 16
#define NU 8
#define PST 18
#define WPITCH 520   // shorts per 512-wide row (bank shift 4/row -> <=2-way)
#define XPITCH 104   // shorts per 96-wide row

// ---------------- ws layout (float offsets) ----------------
#define OFF_HBUF0 0
#define OFF_HBUF1 (2*BATCH*HID)
#define OFF_CBUF0 (OFF_HBUF1 + 2*BATCH*HID)
#define OFF_CBUF1 (OFF_CBUF0 + BATCH*HID)
#define OFF_BAR   (OFF_CBUF1 + BATCH*HID)      // 2 layers x 4 bg x 64 int slots
#define OFF_STATE_END (OFF_BAR + 512)
#define OFF_WOT   OFF_STATE_END                // W_out^T [512][128]
#define OFF_HIST  (OFF_WOT + HID*128)          // layer0 h chunk [64][CT][512]
#define OFF_XPS   (OFF_HIST + BATCH*CT*HID)    // per-WG xp slices: 256 x [512][32]
// total = OFF_XPS + 256*512*32 = 5,505,536 floats ~= 22.0 MB

typedef short s16x8 __attribute__((ext_vector_type(8)));
typedef float f32x4 __attribute__((ext_vector_type(4)));

__device__ __forceinline__ float sigm(float x)  { return 1.f / (1.f + __expf(-x)); }
__device__ __forceinline__ float tanh_f(float x){ return 1.f - 2.f / (__expf(2.f * x) + 1.f); }

__device__ __forceinline__ unsigned short f2b(float f) {      // RNE f32->bf16
    unsigned u = __float_as_uint(f);
    u += 0x7fffu + ((u >> 16) & 1u);
    return (unsigned short)(u >> 16);
}
__device__ __forceinline__ void split2(float f, unsigned short* hi, unsigned short* lo) {
    unsigned short h = f2b(f);
    float r = f - __uint_as_float((unsigned)h << 16);
    *hi = h; *lo = f2b(r);
}
__device__ __forceinline__ unsigned long long pack4(unsigned short a, unsigned short b,
                                                    unsigned short c, unsigned short d) {
    return (unsigned long long)a | ((unsigned long long)b << 16) |
           ((unsigned long long)c << 32) | ((unsigned long long)d << 48);
}
// coherent (cross-XCD) access via agent-scope relaxed atomics (sc1 path, proven R2)
__device__ __forceinline__ unsigned long long ld_coh64(const float* p) {
    return __hip_atomic_load((unsigned long long*)p, __ATOMIC_RELAXED, __HIP_MEMORY_SCOPE_AGENT);
}
__device__ __forceinline__ void st_coh(float* p, float v) {
    __hip_atomic_store(p, v, __ATOMIC_RELAXED, __HIP_MEMORY_SCOPE_AGENT);
}
__device__ __forceinline__ int ld_slot(int* p) {
    return __hip_atomic_load(p, __ATOMIC_RELAXED, __HIP_MEMORY_SCOPE_AGENT);
}
__device__ __forceinline__ void st_slot(int* p, int v) {
    __hip_atomic_store(p, v, __ATOMIC_RELAXED, __HIP_MEMORY_SCOPE_AGENT);
}

// stage one 32x512 f32 weight slice (permuted gate rows) into hi/lo bf16 LDS
__device__ __forceinline__ void stage_w512(const float* __restrict__ W, int u0,
                                           unsigned short* Dhi, unsigned short* Dlo, int tid) {
    int row = tid >> 4, seg = tid & 15;                    // 32 rows x 16 segs of 32
    int grow = (row >> 3) * HID + u0 + (row & 7);
    const float* src = W + (size_t)grow * HID + seg * 32;
    unsigned short* dh = Dhi + row * WPITCH + seg * 32;
    unsigned short* dl = Dlo + row * WPITCH + seg * 32;
#pragma unroll
    for (int q = 0; q < 8; ++q) {
        float4 v = *(const float4*)(src + q * 4);
        unsigned short h0,h1,h2,h3,l0,l1,l2,l3;
        split2(v.x,&h0,&l0); split2(v.y,&h1,&l1); split2(v.z,&h2,&l2); split2(v.w,&h3,&l3);
        *(unsigned long long*)(dh + q * 4) = pack4(h0,h1,h2,h3);
        *(unsigned long long*)(dl + q * 4) = pack4(l0,l1,l2,l3);
    }
}

// =====================================================================
// prep: W_out^T only
// =====================================================================
__global__ void prep_kernel(const float* __restrict__ Wout, float* __restrict__ Wot) {
    int idx = blockIdx.x * 256 + threadIdx.x;      // 65536
    int k = idx >> 7, o = idx & 127;
    Wot[idx] = Wout[(size_t)o * HID + k];
}

// =====================================================================
// rec0: layer-0 LSTM, x-projection fused (K=96), MFMA bf16x3. Cooperative.
// =====================================================================
__global__ __launch_bounds__(512, 2)
void rec0_kernel(const float* __restrict__ prim, const float* __restrict__ aux,
                 const float* __restrict__ Wih0, const float* __restrict__ Whh0,
                 const float* __restrict__ bih0, const float* __restrict__ bhh0,
                 float* __restrict__ hbuf, float* __restrict__ cbuf,
                 float* __restrict__ hist, int* __restrict__ bar, int chunk)
{
    __shared__ __align__(16) unsigned short Whi[32*WPITCH], Wlo[32*WPITCH];
    __shared__ __align__(16) unsigned short Hhi[NB*WPITCH], Hlo[NB*WPITCH];
    __shared__ __align__(16) unsigned short Xwhi[32*XPITCH], Xwlo[32*XPITCH];
    __shared__ __align__(16) unsigned short Xhi[NB*XPITCH], Xlo[NB*XPITCH];
    __shared__ float Ps[32*PST];
    __shared__ float Cs[NB*NU];
    __shared__ float Bsum[32];

    const int tid = threadIdx.x;
    const int wg  = blockIdx.x;
    const int bg  = wg & 3, ug = wg >> 2;
    const int b0  = bg * NB, u0 = ug * NU;
    int* mybar = bar + bg * 64;

    stage_w512(Whh0, u0, Whi, Wlo, tid);
    for (int i = tid; i < 32 * DIN; i += 512) {        // W_ih0 slice
        int row = i / DIN, k = i - row * DIN;
        int grow = (row >> 3) * HID + u0 + (row & 7);
        unsigned short h, l; split2(Wih0[(size_t)grow * DIN + k], &h, &l);
        Xwhi[row * XPITCH + k] = h; Xwlo[row * XPITCH + k] = l;
    }
    if (tid < 32) {
        int grow = (tid >> 3) * HID + u0 + (tid & 7);
        Bsum[tid] = bih0[grow] + bhh0[grow];
    }
    for (int i = tid; i < NB * DAUX; i += 512) {       // aux time-invariant
        int b = i >> 5, k = i & 31;
        unsigned short h, l; split2(aux[(size_t)(b0 + b) * DAUX + k], &h, &l);
        Xhi[b * XPITCH + DPRIM + k] = h; Xlo[b * XPITCH + DPRIM + k] = l;
    }
    if (tid < NB * NU) Cs[tid] = cbuf[(size_t)(b0 + (tid >> 3)) * HID + u0 + (tid & 7)];
    __syncthreads();

    const int lane = tid & 63;
    const int wid  = tid >> 6;
    const int col  = lane & 15;       // A row-within-tile / B col / C col
    const int kg   = lane >> 4;       // k-group

    for (int tl = 0; tl < CT; ++tl) {
        const int t = chunk * CT + tl;
        const int p = t & 1;
        const float* hprev = hbuf + (size_t)(p ^ 1) * (BATCH * HID);

        // ---- stage x(t) (h-independent, before the wait) ----
        if (tid < 256) {
            int b = tid >> 4, k4 = (tid & 15) * 4;
            float4 v = *(const float4*)(prim + ((size_t)(b0 + b) * SEQ + t) * DPRIM + k4);
            unsigned short h0,h1,h2,h3,l0,l1,l2,l3;
            split2(v.x,&h0,&l0); split2(v.y,&h1,&l1); split2(v.z,&h2,&l2); split2(v.w,&h3,&l3);
            *(unsigned long long*)(Xhi + b * XPITCH + k4) = pack4(h0,h1,h2,h3);
            *(unsigned long long*)(Xlo + b * XPITCH + k4) = pack4(l0,l1,l2,l3);
        }
        // ---- wait for h(t-1): 64 slots polled by wave 0 ----
        if (tid < 64) {
            while (true) {
                int v = ld_slot(mybar + tid);
                if (__all(v >= t)) break;
                __builtin_amdgcn_s_sleep(1);
            }
        }
        __syncthreads();
        // ---- stage h(t-1): coherent u64 loads -> bf16 hi/lo LDS ----
        {
            int b = tid >> 5, kb = (tid & 31) * 16;
            const float* hp = hprev + (size_t)(b0 + b) * HID + kb;
            float v[16];
#pragma unroll
            for (int q = 0; q < 8; ++q) {
                unsigned long long w = ld_coh64(hp + q * 2);
                v[q*2]   = __uint_as_float((unsigned)w);
                v[q*2+1] = __uint_as_float((unsigned)(w >> 32));
            }
            unsigned short hh[16], ll[16];
#pragma unroll
            for (int q = 0; q < 16; ++q) split2(v[q], &hh[q], &ll[q]);
            unsigned short* dh = Hhi + b * WPITCH + kb;
            unsigned short* dl = Hlo + b * WPITCH + kb;
#pragma unroll
            for (int q = 0; q < 4; ++q) {
                *(unsigned long long*)(dh + q*4) = pack4(hh[q*4],hh[q*4+1],hh[q*4+2],hh[q*4+3]);
                *(unsigned long long*)(dl + q*4) = pack4(ll[q*4],ll[q*4+1],ll[q*4+2],ll[q*4+3]);
            }
        }
        __syncthreads();
        // ---- MFMA: waves 0,1 compute D[32][16] = W*h + Wx*x (+bias) ----
        if (wid < 2) {
            const int r0 = wid * 16 + kg * 4;
            f32x4 acc;
            acc[0] = Bsum[r0+0]; acc[1] = Bsum[r0+1]; acc[2] = Bsum[r0+2]; acc[3] = Bsum[r0+3];
            const unsigned short* wah = Whi + (size_t)(wid*16 + col) * WPITCH;
            const unsigned short* wal = Wlo + (size_t)(wid*16 + col) * WPITCH;
            const unsigned short* hbh = Hhi + (size_t)col * WPITCH;
            const unsigned short* hbl = Hlo + (size_t)col * WPITCH;
#pragma unroll
            for (int kt = 0; kt < 16; ++kt) {
                int ko = kt * 32 + kg * 8;
                s16x8 ah = *(const s16x8*)(wah + ko);
                s16x8 al = *(const s16x8*)(wal + ko);
                s16x8 bh = *(const s16x8*)(hbh + ko);
                s16x8 bl = *(const s16x8*)(hbl + ko);
                acc = __builtin_amdgcn_mfma_f32_16x16x32_bf16(ah, bh, acc, 0, 0, 0);
                acc = __builtin_amdgcn_mfma_f32_16x16x32_bf16(ah, bl, acc, 0, 0, 0);
                acc = __builtin_amdgcn_mfma_f32_16x16x32_bf16(al, bh, acc, 0, 0, 0);
            }
            const unsigned short* xah = Xwhi + (size_t)(wid*16 + col) * XPITCH;
            const unsigned short* xal = Xwlo + (size_t)(wid*16 + col) * XPITCH;
            const unsigned short* xbh = Xhi + (size_t)col * XPITCH;
            const unsigned short* xbl = Xlo + (size_t)col * XPITCH;
#pragma unroll
            for (int kt = 0; kt < 3; ++kt) {
                int ko = kt * 32 + kg * 8;
                s16x8 ah = *(const s16x8*)(xah + ko);
                s16x8 al = *(const s16x8*)(xal + ko);
                s16x8 bh = *(const s16x8*)(xbh + ko);
                s16x8 bl = *(const s16x8*)(xbl + ko);
                acc = __builtin_amdgcn_mfma_f32_16x16x32_bf16(ah, bh, acc, 0, 0, 0);
                acc = __builtin_amdgcn_mfma_f32_16x16x32_bf16(ah, bl, acc, 0, 0, 0);
                acc = __builtin_amdgcn_mfma_f32_16x16x32_bf16(al, bh, acc, 0, 0, 0);
            }
#pragma unroll
            for (int j = 0; j < 4; ++j) Ps[(r0 + j) * PST + col] = acc[j];
        }
        __syncthreads();
        // ---- activations + state update + coherent publish ----
        if (tid < 128) {
            int b = tid >> 3, u = tid & 7;
            float gi = Ps[(u)      * PST + b];
            float gf = Ps[(8  + u) * PST + b];
            float gg = Ps[(16 + u) * PST + b];
            float go = Ps[(24 + u) * PST + b];
            float si = sigm(gi), sf = sigm(gf), so = sigm(go);
            float tg = tanh_f(gg);
            float cN = sf * Cs[b * NU + u] + si * tg;
            Cs[b * NU + u] = cN;
            float hN = so * tanh_f(cN);
            size_t gb = (size_t)(b0 + b);
            st_coh(hbuf + (size_t)p * (BATCH * HID) + gb * HID + u0 + u, hN);
            hist[(gb * CT + tl) * HID + u0 + u] = hN;
        }
        __syncthreads();                 // drains vmcnt -> h stores globally visible
        if (tid == 0) st_slot(mybar + ug, t + 1);
    }
    if (tid < NB * NU) cbuf[(size_t)(b0 + (tid >> 3)) * HID + u0 + (tid & 7)] = Cs[tid];
}

// =====================================================================
// rec1: per chunk: (1) xp slice GEMM (W_ih1 * hist^T, bf16x3 MFMA, all 8 waves),
//       (2) recurrent loop (same structure as rec0, xp read from own slice).
// =====================================================================
__global__ __launch_bounds__(512, 2)
void rec1_kernel(const float* __restrict__ hist, const float* __restrict__ Wih1,
                 const float* __restrict__ Whh1, const float* __restrict__ bih1,
                 const float* __restrict__ bhh1, float* __restrict__ hbuf,
                 float* __restrict__ cbuf, float* __restrict__ xps,
                 int* __restrict__ bar, int chunk)
{
    __shared__ __align__(16) unsigned short Whi[32*WPITCH], Wlo[32*WPITCH];
    __shared__ __align__(16) unsigned short Hhi[NB*WPITCH], Hlo[NB*WPITCH];
    __shared__ float Ps[32*PST];
    __shared__ float Cs[NB*NU];
    __shared__ float Bsum[32];

    const int tid = threadIdx.x;
    const int wg  = blockIdx.x;
    const int bg  = wg & 3, ug = wg >> 2;
    const int b0  = bg * NB, u0 = ug * NU;
    int* mybar = bar + bg * 64;
    float* xpw = xps + (size_t)wg * (512 * 32);

    const int lane = tid & 63;
    const int wid  = tid >> 6;
    const int col  = lane & 15;
    const int kg   = lane >> 4;

    if (tid < 32) {
        int grow = (tid >> 3) * HID + u0 + (tid & 7);
        Bsum[tid] = bih1[grow] + bhh1[grow];
    }
    if (tid < NB * NU) Cs[tid] = cbuf[(size_t)(b0 + (tid >> 3)) * HID + u0 + (tid & 7)];

    // ---- phase 1: xp slice = W_ih1(32 rows) x hist^T (512 m-rows) ----
    stage_w512(Wih1, u0, Whi, Wlo, tid);
    __syncthreads();
    {
        f32x4 acc[4][2];
#pragma unroll
        for (int m = 0; m < 4; ++m)
#pragma unroll
            for (int n = 0; n < 2; ++n) { acc[m][n][0]=0.f; acc[m][n][1]=0.f; acc[m][n][2]=0.f; acc[m][n][3]=0.f; }

        for (int kt = 0; kt < 16; ++kt) {
            int ko = kt * 32 + kg * 8;
            s16x8 ah[2], al[2];
#pragma unroll
            for (int n = 0; n < 2; ++n) {
                ah[n] = *(const s16x8*)(Whi + (size_t)(n*16 + col) * WPITCH + ko);
                al[n] = *(const s16x8*)(Wlo + (size_t)(n*16 + col) * WPITCH + ko);
            }
#pragma unroll
            for (int m = 0; m < 4; ++m) {
                int mrow = wid * 64 + m * 16 + col;           // local m in [0,512)
                const float* hp = hist + ((size_t)(b0 * CT) + mrow) * HID + ko;
                float4 v0 = *(const float4*)(hp);
                float4 v1 = *(const float4*)(hp + 4);
                unsigned short hh[8], ll[8];
                split2(v0.x,&hh[0],&ll[0]); split2(v0.y,&hh[1],&ll[1]);
                split2(v0.z,&hh[2],&ll[2]); split2(v0.w,&hh[3],&ll[3]);
                split2(v1.x,&hh[4],&ll[4]); split2(v1.y,&hh[5],&ll[5]);
                split2(v1.z,&hh[6],&ll[6]); split2(v1.w,&hh[7],&ll[7]);
                s16x8 bh, bl;
#pragma unroll
                for (int j = 0; j < 8; ++j) { bh[j] = (short)hh[j]; bl[j] = (short)ll[j]; }
#pragma unroll
                for (int n = 0; n < 2; ++n) {
                    acc[m][n] = __builtin_amdgcn_mfma_f32_16x16x32_bf16(ah[n], bh, acc[m][n], 0, 0, 0);
                    acc[m][n] = __builtin_amdgcn_mfma_f32_16x16x32_bf16(ah[n], bl, acc[m][n], 0, 0, 0);
                    acc[m][n] = __builtin_amdgcn_mfma_f32_16x16x32_bf16(al[n], bh, acc[m][n], 0, 0, 0);
                }
            }
        }
#pragma unroll
        for (int m = 0; m < 4; ++m)
#pragma unroll
            for (int n = 0; n < 2; ++n) {
                int mrow = wid * 64 + m * 16 + col;
                int nc = n * 16 + kg * 4;
                float4 o;
                o.x = acc[m][n][0] + Bsum[nc+0];
                o.y = acc[m][n][1] + Bsum[nc+1];
                o.z = acc[m][n][2] + Bsum[nc+2];
                o.w = acc[m][n][3] + Bsum[nc+3];
                *(float4*)(xpw + (size_t)mrow * 32 + nc) = o;
            }
    }
    __syncthreads();
    // ---- phase 2: recurrent ----
    stage_w512(Whh1, u0, Whi, Wlo, tid);
    __syncthreads();

    for (int tl = 0; tl < CT; ++tl) {
        const int t = chunk * CT + tl;
        const int p = t & 1;
        const float* hprev = hbuf + (size_t)(p ^ 1) * (BATCH * HID);

        float xq0 = 0.f, xq1 = 0.f, xq2 = 0.f, xq3 = 0.f;    // xp prefetch (own slice)
        if (tid < 128) {
            int b = tid >> 3, u = tid & 7;
            const float* xr = xpw + (size_t)(b * 32 + tl) * 32 + u;
            xq0 = xr[0]; xq1 = xr[8]; xq2 = xr[16]; xq3 = xr[24];
        }
        if (tid < 64) {
            while (true) {
                int v = ld_slot(mybar + tid);
                if (__all(v >= t)) break;
                __builtin_amdgcn_s_sleep(1);
            }
        }
        __syncthreads();
        {
            int b = tid >> 5, kb = (tid & 31) * 16;
            const float* hp = hprev + (size_t)(b0 + b) * HID + kb;
            float v[16];
#pragma unroll
            for (int q = 0; q < 8; ++q) {
                unsigned long long w = ld_coh64(hp + q * 2);
                v[q*2]   = __uint_as_float((unsigned)w);
                v[q*2+1] = __uint_as_float((unsigned)(w >> 32));
            }
            unsigned short hh[16], ll[16];
#pragma unroll
            for (int q = 0; q < 16; ++q) split2(v[q], &hh[q], &ll[q]);
            unsigned short* dh = Hhi + b * WPITCH + kb;
            unsigned short* dl = Hlo + b * WPITCH + kb;
#pragma unroll
            for (int q = 0; q < 4; ++q) {
                *(unsigned long long*)(dh + q*4) = pack4(hh[q*4],hh[q*4+1],hh[q*4+2],hh[q*4+3]);
                *(unsigned long long*)(dl + q*4) = pack4(ll[q*4],ll[q*4+1],ll[q*4+2],ll[q*4+3]);
            }
        }
        __syncthreads();
        if (wid < 2) {
            const int r0 = wid * 16 + kg * 4;
            f32x4 acc; acc[0]=0.f; acc[1]=0.f; acc[2]=0.f; acc[3]=0.f;
            const unsigned short* wah = Whi + (size_t)(wid*16 + col) * WPITCH;
            const unsigned short* wal = Wlo + (size_t)(wid*16 + col) * WPITCH;
            const unsigned short* hbh = Hhi + (size_t)col * WPITCH;
            const unsigned short* hbl = Hlo + (size_t)col * WPITCH;
#pragma unroll
            for (int kt = 0; kt < 16; ++kt) {
                int ko = kt * 32 + kg * 8;
                s16x8 ah = *(const s16x8*)(wah + ko);
                s16x8 al = *(const s16x8*)(wal + ko);
                s16x8 bh = *(const s16x8*)(hbh + ko);
                s16x8 bl = *(const s16x8*)(hbl + ko);
                acc = __builtin_amdgcn_mfma_f32_16x16x32_bf16(ah, bh, acc, 0, 0, 0);
                acc = __builtin_amdgcn_mfma_f32_16x16x32_bf16(ah, bl, acc, 0, 0, 0);
                acc = __builtin_amdgcn_mfma_f32_16x16x32_bf16(al, bh, acc, 0, 0, 0);
            }
#pragma unroll
            for (int j = 0; j < 4; ++j) Ps[(r0 + j) * PST + col] = acc[j];
        }
        __syncthreads();
        if (tid < 128) {
            int b = tid >> 3, u = tid & 7;
            float gi = Ps[(u)      * PST + b] + xq0;
            float gf = Ps[(8  + u) * PST + b] + xq1;
            float gg = Ps[(16 + u) * PST + b] + xq2;
            float go = Ps[(24 + u) * PST + b] + xq3;
            float si = sigm(gi), sf = sigm(gf), so = sigm(go);
            float tg = tanh_f(gg);
            float cN = sf * Cs[b * NU + u] + si * tg;
            Cs[b * NU + u] = cN;
            float hN = so * tanh_f(cN);
            st_coh(hbuf + (size_t)p * (BATCH * HID) + (size_t)(b0 + b) * HID + u0 + u, hN);
        }
        __syncthreads();
        if (tid == 0) st_slot(mybar + ug, t + 1);
    }
    if (tid < NB * NU) cbuf[(size_t)(b0 + (tid >> 3)) * HID + u0 + (tid & 7)] = Cs[tid];
}

// =====================================================================
// output projection
// =====================================================================
__global__ void outproj_kernel(const float* __restrict__ hlast, const float* __restrict__ Wot,
                               const float* __restrict__ bout, float* __restrict__ out)
{
    __shared__ float hs[HID];
    int b = blockIdx.x;
    for (int i = threadIdx.x; i < HID; i += 128) hs[i] = hlast[(size_t)b * HID + i];
    __syncthreads();
    int o = threadIdx.x;
    float acc = bout[o];
#pragma unroll 8
    for (int k = 0; k < HID; ++k) acc = fmaf(hs[k], Wot[k * 128 + o], acc);
    out[b * 128 + o] = acc;
}

// =====================================================================
extern "C" void kernel_launch(void* const* d_in, const int* in_sizes, int n_in,
                              void* d_out, int out_size, void* d_ws, size_t ws_size,
                              hipStream_t stream)
{
    const float* prim = (const float*)d_in[0];
    const float* aux  = (const float*)d_in[1];
    const float* Wih0 = (const float*)d_in[2];
    const float* Whh0 = (const float*)d_in[3];
    const float* bih0 = (const float*)d_in[4];
    const float* bhh0 = (const float*)d_in[5];
    const float* Wih1 = (const float*)d_in[6];
    const float* Whh1 = (const float*)d_in[7];
    const float* bih1 = (const float*)d_in[8];
    const float* bhh1 = (const float*)d_in[9];
    const float* Wout = (const float*)d_in[10];
    const float* bout = (const float*)d_in[11];
    float* out = (float*)d_out;
    float* ws  = (float*)d_ws;

    float* hbuf0 = ws + OFF_HBUF0;
    float* hbuf1 = ws + OFF_HBUF1;
    float* cbuf0 = ws + OFF_CBUF0;
    float* cbuf1 = ws + OFF_CBUF1;
    int*   bar0  = (int*)(ws + OFF_BAR);
    int*   bar1  = bar0 + 256;
    float* Wot   = ws + OFF_WOT;
    float* hist  = ws + OFF_HIST;
    float* xpsp  = ws + OFF_XPS;

    hipMemsetAsync(ws, 0, (size_t)OFF_STATE_END * sizeof(float), stream);
    prep_kernel<<<256, 256, 0, stream>>>(Wout, Wot);

    for (int c = 0; c < NCHUNK; ++c) {
        int cc = c;
        void* a0[] = {(void*)&prim, (void*)&aux, (void*)&Wih0, (void*)&Whh0,
                      (void*)&bih0, (void*)&bhh0, (void*)&hbuf0, (void*)&cbuf0,
                      (void*)&hist, (void*)&bar0, (void*)&cc};
        hipLaunchCooperativeKernel((void*)rec0_kernel, dim3(256), dim3(512), a0, 0, stream);

        void* a1[] = {(void*)&hist, (void*)&Wih1, (void*)&Whh1, (void*)&bih1,
                      (void*)&bhh1, (void*)&hbuf1, (void*)&cbuf1, (void*)&xpsp,
                      (void*)&bar1, (void*)&cc};
        hipLaunchCooperativeKernel((void*)rec1_kernel, dim3(256), dim3(512), a1, 0, stream);
    }
    outproj_kernel<<<64, 128, 0, stream>>>(hbuf1 + BATCH * HID, Wot, bout, out);
}

// Round 4
// 3701.390 us; speedup vs baseline: 28.2605x; 1.7296x over previous
//
#include <hip/hip_runtime.h>

// ---------------- problem dims ----------------
#define BATCH 64
#define SEQ   512
#define HID   512
#define DPRIM 64
#define DAUX  32
#define CT    16
#define NCHUNK 32
#define NBAT  32          // batches per WG
#define WP    520         // u16 pitch, 512-wide rows
#define XPI   104         // u16 pitch, 96-wide rows
#define PST   33

// ---------------- ws byte offsets ----------------
#define WS_HB0HI  0u
#define WS_HB0LO  131072u
#define WS_HB1HI  262144u
#define WS_HB1LO  393216u
#define WS_SLOT0  524288u
#define WS_SLOT1  526336u
#define WS_GDONE  528384u
#define WS_XPD    530432u
#define WS_STATE_END 532480u
#define WS_PHH0HI 532480u
#define WS_PHH0LO 2629632u
#define WS_PHH1HI 4726784u
#define WS_PHH1LO 6823936u
#define WS_PIH1HI 8921088u
#define WS_PIH1LO 11018240u
#define WS_PIH0HI 13115392u
#define WS_PIH0LO 13508608u
#define WS_BSUM0  13901824u
#define WS_BSUM1  13910016u
#define WS_WOT    13918208u
#define WS_HIST   14180352u   // u32[2][64][CT][512]
#define WS_XP0    18374656u   // f32[128][16384]
#define WS_XP1    26763264u   // f32[128][16384]
// total ~35.2 MB

typedef short s16x8 __attribute__((ext_vector_type(8)));
typedef float f32x4 __attribute__((ext_vector_type(4)));
typedef unsigned long long u64t;
typedef unsigned int u32t;
typedef unsigned short u16t;

__device__ __forceinline__ float sigm(float x)  { return 1.f / (1.f + __expf(-x)); }
__device__ __forceinline__ float tanh_f(float x){ return 1.f - 2.f / (__expf(2.f * x) + 1.f); }
__device__ __forceinline__ u16t f2b(float f) {
    u32t u = __float_as_uint(f);
    u += 0x7fffu + ((u >> 16) & 1u);
    return (u16t)(u >> 16);
}
__device__ __forceinline__ void split2(float f, u16t* hi, u16t* lo) {
    u16t h = f2b(f);
    float r = f - __uint_as_float((u32t)h << 16);
    *hi = h; *lo = f2b(r);
}
// coherent (cross-XCD, sc1/MALL) access — proven R2/R3
__device__ __forceinline__ u64t ld_coh64(const u64t* p) {
    return __hip_atomic_load(p, __ATOMIC_RELAXED, __HIP_MEMORY_SCOPE_AGENT);
}
__device__ __forceinline__ float ld_cohf(const float* p) {
    return __hip_atomic_load(p, __ATOMIC_RELAXED, __HIP_MEMORY_SCOPE_AGENT);
}
__device__ __forceinline__ void st_coh32(u32t* p, u32t v) {
    __hip_atomic_store(p, v, __ATOMIC_RELAXED, __HIP_MEMORY_SCOPE_AGENT);
}
__device__ __forceinline__ void st_cohf(float* p, float v) {
    __hip_atomic_store(p, v, __ATOMIC_RELAXED, __HIP_MEMORY_SCOPE_AGENT);
}
__device__ __forceinline__ int ld_slot(const int* p) {
    return __hip_atomic_load(p, __ATOMIC_RELAXED, __HIP_MEMORY_SCOPE_AGENT);
}
__device__ __forceinline__ void st_slot(int* p, int v) {
    __hip_atomic_store(p, v, __ATOMIC_RELAXED, __HIP_MEMORY_SCOPE_AGENT);
}
#define MFMA16(a,b,c) __builtin_amdgcn_mfma_f32_16x16x32_bf16(a,b,c,0,0,0)

// pure-copy W staging from pre-split planes: LDS row rl = gate*8+u
__device__ __forceinline__ void stage_w(const u16t* ph, const u16t* pl,
                                        u16t* dh, u16t* dl, int u0, int tid) {
    int rl = tid >> 4, j = tid & 15;
    int grow = (rl >> 3) * HID + u0 + (rl & 7);
    const u64t* sh = (const u64t*)(ph + (size_t)grow * HID);
    const u64t* sl = (const u64t*)(pl + (size_t)grow * HID);
    u64t* th = (u64t*)(dh + (size_t)rl * WP);
    u64t* tl2 = (u64t*)(dl + (size_t)rl * WP);
#pragma unroll
    for (int q = 0; q < 8; ++q) { int s = q * 16 + j; th[s] = sh[s]; tl2[s] = sl[s]; }
}

// =====================================================================
// prep: split all weights to hi/lo bf16 planes; bias sums; W_out^T
// =====================================================================
__global__ void prep_kernel(const float* __restrict__ Wih0, const float* __restrict__ Whh0,
                            const float* __restrict__ bih0, const float* __restrict__ bhh0,
                            const float* __restrict__ Wih1, const float* __restrict__ Whh1,
                            const float* __restrict__ bih1, const float* __restrict__ bhh1,
                            const float* __restrict__ Wout, char* __restrict__ ws)
{
    int idx = blockIdx.x * 256 + threadIdx.x;          // 0..1048575
    u16t h, l;
    split2(Whh0[idx], &h, &l);
    ((u16t*)(ws + WS_PHH0HI))[idx] = h; ((u16t*)(ws + WS_PHH0LO))[idx] = l;
    split2(Whh1[idx], &h, &l);
    ((u16t*)(ws + WS_PHH1HI))[idx] = h; ((u16t*)(ws + WS_PHH1LO))[idx] = l;
    split2(Wih1[idx], &h, &l);
    ((u16t*)(ws + WS_PIH1HI))[idx] = h; ((u16t*)(ws + WS_PIH1LO))[idx] = l;
    if (idx < 2048 * 96) {
        split2(Wih0[idx], &h, &l);
        ((u16t*)(ws + WS_PIH0HI))[idx] = h; ((u16t*)(ws + WS_PIH0LO))[idx] = l;
    }
    if (idx < 2048) {
        ((float*)(ws + WS_BSUM0))[idx] = bih0[idx] + bhh0[idx];
        ((float*)(ws + WS_BSUM1))[idx] = bih1[idx] + bhh1[idx];
    }
    if (idx < 65536) {
        ((float*)(ws + WS_WOT))[idx] = Wout[(size_t)(idx & 127) * HID + (idx >> 7)];
    }
}

// =====================================================================
// one recurrent step (shared by both layers)
// =====================================================================
__device__ __forceinline__ void do_step(
    int t, int c, int tl, int tid, int wid, int col, int kg,
    int b0, int u0, int ug,
    u16t* Whi, u16t* Wlo, u16t* Hhi, u16t* Hlo, float* Ps, float* Cs,
    u16t* hbhi, u16t* hblo, int* slots_self,
    const float* xp_self, bool coh_xq, u32t* hist_ring)
{
    const int p = t & 1;
    // xq prefetch (chunk-static, no dependency on the poll)
    float xq0 = 0.f, xq1 = 0.f, xq2 = 0.f, xq3 = 0.f;
    if (tid < 256) {
        int b = tid >> 3, u = tid & 7;
        const float* xr = xp_self + (size_t)(b * CT + tl) * 32;
        if (coh_xq) {
            xq0 = ld_cohf(xr + u);      xq1 = ld_cohf(xr + 8 + u);
            xq2 = ld_cohf(xr + 16 + u); xq3 = ld_cohf(xr + 24 + u);
        } else {
            xq0 = xr[u]; xq1 = xr[8 + u]; xq2 = xr[16 + u]; xq3 = xr[24 + u];
        }
    }
    // wait for h(t-1) from all 64 unit-group producers of this batch-group
    if (tid < 64) {
        while (true) {
            int v = ld_slot(slots_self + tid * 4);
            if (__all(v >= t)) break;
            __builtin_amdgcn_s_sleep(1);
        }
    }
    __syncthreads();
    // stage h(t-1): pure u64 copy (producers pre-split hi/lo planes)
    {
        int b = tid >> 4, j = tid & 15;
        const u64t* sh = (const u64t*)(hbhi + (size_t)((p ^ 1) * BATCH + b0 + b) * HID);
        const u64t* sl = (const u64t*)(hblo + (size_t)((p ^ 1) * BATCH + b0 + b) * HID);
        u64t* th = (u64t*)(Hhi + (size_t)b * WP);
        u64t* tl2 = (u64t*)(Hlo + (size_t)b * WP);
#pragma unroll
        for (int q = 0; q < 8; ++q) {
            int s = q * 16 + j;
            u64t vh = ld_coh64(sh + s);
            u64t vl = ld_coh64(sl + s);
            th[s] = vh; tl2[s] = vl;
        }
    }
    __syncthreads();
    // MFMA: 4 waves, D[32 rows][32 batches], bf16x3, 2 independent chains
    if (wid < 4) {
        int rt = wid >> 1, bt = wid & 1;
        const u16t* wah = Whi + (size_t)(rt * 16 + col) * WP;
        const u16t* wal = Wlo + (size_t)(rt * 16 + col) * WP;
        const u16t* hbh = Hhi + (size_t)(bt * 16 + col) * WP;
        const u16t* hbl = Hlo + (size_t)(bt * 16 + col) * WP;
        f32x4 a0 = {0.f, 0.f, 0.f, 0.f}, a1 = {0.f, 0.f, 0.f, 0.f};
#pragma unroll
        for (int k2 = 0; k2 < 8; ++k2) {
            int ko0 = k2 * 64 + kg * 8;
            int ko1 = ko0 + 32;
            s16x8 ah0 = *(const s16x8*)(wah + ko0), al0 = *(const s16x8*)(wal + ko0);
            s16x8 bh0 = *(const s16x8*)(hbh + ko0), bl0 = *(const s16x8*)(hbl + ko0);
            s16x8 ah1 = *(const s16x8*)(wah + ko1), al1 = *(const s16x8*)(wal + ko1);
            s16x8 bh1 = *(const s16x8*)(hbh + ko1), bl1 = *(const s16x8*)(hbl + ko1);
            a0 = MFMA16(ah0, bh0, a0); a1 = MFMA16(ah1, bh1, a1);
            a0 = MFMA16(ah0, bl0, a0); a1 = MFMA16(ah1, bl1, a1);
            a0 = MFMA16(al0, bh0, a0); a1 = MFMA16(al1, bh1, a1);
        }
        a0 = a0 + a1;
#pragma unroll
        for (int j = 0; j < 4; ++j)
            Ps[(rt * 16 + kg * 4 + j) * PST + bt * 16 + col] = a0[j];
    }
    __syncthreads();
    // activations + state + publish (pre-split hi/lo planes via shfl pack)
    if (tid < 256) {
        int b = tid >> 3, u = tid & 7;
        float gi = Ps[(u)      * PST + b] + xq0;
        float gf = Ps[(8 + u)  * PST + b] + xq1;
        float gg = Ps[(16 + u) * PST + b] + xq2;
        float go = Ps[(24 + u) * PST + b] + xq3;
        float si = sigm(gi), sf = sigm(gf), so = sigm(go);
        float tg = tanh_f(gg);
        float cN = sf * Cs[tid] + si * tg;
        Cs[tid] = cN;
        float hN = so * tanh_f(cN);
        u16t hi, lo; split2(hN, &hi, &lo);
        int e = (b0 + b) * HID + u0 + u;
        int ph = __shfl_xor((int)hi, 1);
        int pl = __shfl_xor((int)lo, 1);
        if ((u & 1) == 0) {
            st_coh32((u32t*)hbhi + (size_t)p * (BATCH * HID / 2) + (e >> 1),
                     (u32t)hi | ((u32t)ph << 16));
            st_coh32((u32t*)hblo + (size_t)p * (BATCH * HID / 2) + (e >> 1),
                     (u32t)lo | ((u32t)pl << 16));
        }
        if (hist_ring) {
            st_coh32(hist_ring + ((size_t)((c & 1) * BATCH + b0 + b) * CT + tl) * HID + u0 + u,
                     ((u32t)hi << 16) | (u32t)lo);
        }
    }
    __syncthreads();   // drains vmcnt: publishes globally visible
    if (tid == 0) st_slot(slots_self + ug * 4, t + 1);
}

// =====================================================================
// mega kernel: 256 WGs resident. WG 0..127 = layer0 (chunk c),
// WG 128..255 = layer1 (chunk c, consuming hist chunk c, one chunk behind).
// =====================================================================
__global__ __launch_bounds__(512, 2)
void mega_kernel(const float* __restrict__ prim, const float* __restrict__ aux,
                 char* __restrict__ ws)
{
    __shared__ __align__(16) unsigned char smem[151808];
    u16t* Whi  = (u16t*)smem;
    u16t* Wlo  = (u16t*)(smem + 33280);
    u16t* Hhi  = (u16t*)(smem + 66560);
    u16t* Hlo  = (u16t*)(smem + 99840);
    u16t* XWhi = (u16t*)(smem + 133120);
    u16t* XWlo = (u16t*)(smem + 139776);
    float* Ps  = (float*)(smem + 146432);
    float* Cs  = (float*)(smem + 150656);
    float* Bs  = (float*)(smem + 151680);

    const int tid  = threadIdx.x;
    const int wgid = blockIdx.x;
    const int layer = wgid >> 7;
    const int lwg  = wgid & 127;
    const int bg   = (lwg >> 2) & 1;
    const int ug   = ((lwg >> 3) << 2) | (lwg & 3);
    const int b0   = bg * NBAT;
    const int u0   = ug * 8;
    const int lane = tid & 63;
    const int wid  = tid >> 6;
    const int col  = lane & 15;
    const int kg   = lane >> 4;

    u16t* hbhi = (u16t*)(ws + (layer ? WS_HB1HI : WS_HB0HI));
    u16t* hblo = (u16t*)(ws + (layer ? WS_HB1LO : WS_HB0LO));
    int* slots_self = (int*)(ws + (layer ? WS_SLOT1 : WS_SLOT0)) + bg * 256;
    int* slots_l0   = (int*)(ws + WS_SLOT0) + bg * 256;
    int* gdone      = (int*)(ws + WS_GDONE) + bg * 256;
    int* xpd        = (int*)(ws + WS_XPD)   + bg * 256;
    const float* bsum = (const float*)(ws + (layer ? WS_BSUM1 : WS_BSUM0));
    u32t* hist = (u32t*)(ws + WS_HIST);
    float* xpregion = (float*)(ws + (layer ? WS_XP1 : WS_XP0));
    float* xp_self = xpregion + (size_t)lwg * 16384;

    // ---- one-time init ----
    if (tid < 256) Cs[tid] = 0.f;
    if (tid < 32) {
        int grow = (tid >> 3) * HID + u0 + (tid & 7);
        Bs[tid] = bsum[grow];
    }
    if (layer == 0) {
        stage_w((u16t*)(ws + WS_PHH0HI), (u16t*)(ws + WS_PHH0LO), Whi, Wlo, u0, tid);
        for (int s = tid; s < 32 * 24; s += 512) {     // W_ih0 slice (96 = 24 u64)
            int rl = s / 24, sl = s % 24;
            int grow = (rl >> 3) * HID + u0 + (rl & 7);
            u64t v  = *((const u64t*)((u16t*)(ws + WS_PIH0HI) + (size_t)grow * 96) + sl);
            u64t v2 = *((const u64t*)((u16t*)(ws + WS_PIH0LO) + (size_t)grow * 96) + sl);
            *((u64t*)(XWhi + (size_t)rl * XPI) + sl) = v;
            *((u64t*)(XWlo + (size_t)rl * XPI) + sl) = v2;
        }
    }
    __syncthreads();

    if (layer == 0) {
        // =========== LAYER 0 ===========
        for (int c = 0; c < NCHUNK; ++c) {
            // ---- xp0 chunk GEMM: D[512 m][32 rows] = x * W_ih0^T (+bias) ----
            {
                f32x4 acc[4][2];
#pragma unroll
                for (int m4 = 0; m4 < 4; ++m4)
#pragma unroll
                    for (int nt = 0; nt < 2; ++nt)
                        acc[m4][nt] = (f32x4){0.f, 0.f, 0.f, 0.f};
#pragma unroll
                for (int kt = 0; kt < 3; ++kt) {
                    int k0 = kt * 32 + kg * 8;
                    s16x8 ah0 = *(const s16x8*)(XWhi + (size_t)(col) * XPI + k0);
                    s16x8 al0 = *(const s16x8*)(XWlo + (size_t)(col) * XPI + k0);
                    s16x8 ah1 = *(const s16x8*)(XWhi + (size_t)(16 + col) * XPI + k0);
                    s16x8 al1 = *(const s16x8*)(XWlo + (size_t)(16 + col) * XPI + k0);
#pragma unroll
                    for (int m4 = 0; m4 < 4; ++m4) {
                        int bb = wid * 4 + m4;             // local batch 0..31; col = tl
                        float xv[8];
                        if (kt < 2) {
                            const float* pr = prim + ((size_t)(b0 + bb) * SEQ + c * CT + col) * DPRIM + k0;
                            float4 v0 = *(const float4*)pr;
                            float4 v1 = *(const float4*)(pr + 4);
                            xv[0] = v0.x; xv[1] = v0.y; xv[2] = v0.z; xv[3] = v0.w;
                            xv[4] = v1.x; xv[5] = v1.y; xv[6] = v1.z; xv[7] = v1.w;
                        } else {
                            const float* ax = aux + (size_t)(b0 + bb) * DAUX + kg * 8;
                            float4 v0 = *(const float4*)ax;
                            float4 v1 = *(const float4*)(ax + 4);
                            xv[0] = v0.x; xv[1] = v0.y; xv[2] = v0.z; xv[3] = v0.w;
                            xv[4] = v1.x; xv[5] = v1.y; xv[6] = v1.z; xv[7] = v1.w;
                        }
                        u16t hh[8], ll[8];
#pragma unroll
                        for (int j = 0; j < 8; ++j) split2(xv[j], &hh[j], &ll[j]);
                        s16x8 bh, bl;
#pragma unroll
                        for (int j = 0; j < 8; ++j) { bh[j] = (short)hh[j]; bl[j] = (short)ll[j]; }
                        acc[m4][0] = MFMA16(ah0, bh, acc[m4][0]);
                        acc[m4][0] = MFMA16(ah0, bl, acc[m4][0]);
                        acc[m4][0] = MFMA16(al0, bh, acc[m4][0]);
                        acc[m4][1] = MFMA16(ah1, bh, acc[m4][1]);
                        acc[m4][1] = MFMA16(ah1, bl, acc[m4][1]);
                        acc[m4][1] = MFMA16(al1, bh, acc[m4][1]);
                    }
                }
#pragma unroll
                for (int m4 = 0; m4 < 4; ++m4) {
                    int m = (wid * 4 + m4) * 16 + col;
#pragma unroll
                    for (int nt = 0; nt < 2; ++nt)
#pragma unroll
                        for (int j = 0; j < 4; ++j) {
                            int gr = nt * 16 + kg * 4 + j;
                            xp_self[(size_t)m * 32 + gr] = acc[m4][nt][j] + Bs[gr];
                        }
                }
            }
            // ---- ring backpressure: layer1 must have staged hist chunk c-2 ----
            if (c >= 2) {
                if (tid < 64) {
                    while (true) {
                        int v = ld_slot(gdone + tid * 4);
                        if (__all(v >= c - 1)) break;
                        __builtin_amdgcn_s_sleep(1);
                    }
                }
            }
            __syncthreads();
            // ---- steps ----
            for (int tl = 0; tl < CT; ++tl)
                do_step(c * CT + tl, c, tl, tid, wid, col, kg, b0, u0, ug,
                        Whi, Wlo, Hhi, Hlo, Ps, Cs, hbhi, hblo, slots_self,
                        xp_self, false, hist);
        }
    } else {
        // =========== LAYER 1 ===========
        u16t* Bthi = Whi;                 // [64][WP] aliases Whi+Wlo
        u16t* Btlo = Hhi;                 // [64][WP] aliases Hhi+Hlo
        const int gm = ug >> 3, gn = ug & 7;
        for (int c = 0; c < NCHUNK; ++c) {
            // gate: layer0 finished chunk c
            if (tid < 64) {
                while (true) {
                    int v = ld_slot(slots_l0 + tid * 4);
                    if (__all(v >= (c + 1) * CT)) break;
                    __builtin_amdgcn_s_sleep(1);
                }
            }
            __syncthreads();
            // stage B-tile (64 m-rows x 512 k) from hist ring[c&1], unpack hi/lo
            {
                int i = tid >> 3, j = tid & 7;
                int m = gm * 64 + i;
                int gb = b0 + (m >> 4), tl2 = m & 15;
                const u64t* src = (const u64t*)(hist + ((size_t)((c & 1) * BATCH + gb) * CT + tl2) * HID);
                u64t* dh = (u64t*)(Bthi + (size_t)i * WP);
                u64t* dl = (u64t*)(Btlo + (size_t)i * WP);
#pragma unroll
                for (int q = 0; q < 16; ++q) {
                    int g = q * 8 + j;
                    u64t w0 = ld_coh64(src + g * 2);
                    u64t w1 = ld_coh64(src + g * 2 + 1);
                    u32t e0 = (u32t)w0, e1 = (u32t)(w0 >> 32);
                    u32t e2 = (u32t)w1, e3 = (u32t)(w1 >> 32);
                    dh[g] = (u64t)(e0 >> 16) | ((u64t)(e1 >> 16) << 16) |
                            ((u64t)(e2 >> 16) << 32) | ((u64t)(e3 >> 16) << 48);
                    dl[g] = (u64t)(e0 & 0xffffu) | ((u64t)(e1 & 0xffffu) << 16) |
                            ((u64t)(e2 & 0xffffu) << 32) | ((u64t)(e3 & 0xffffu) << 48);
                }
            }
            __syncthreads();
            if (tid == 0) st_slot(gdone + ug * 4, c + 1);   // hist ring slot consumed
            // ---- 2D-tiled xp1 GEMM: tile (gm:64m) x (gn:256n), K=512, bf16x3 ----
            {
                const u16t* pih = (const u16t*)(ws + WS_PIH1HI);
                const u16t* pil = (const u16t*)(ws + WS_PIH1LO);
                int Rb0 = gn * 256 + (wid * 2) * 16 + col;
                int Rb1 = Rb0 + 16;
                int g0 = ((Rb0 >> 3) & 3) * HID + (Rb0 >> 5) * 8 + (Rb0 & 7);
                int g1 = ((Rb1 >> 3) & 3) * HID + (Rb1 >> 5) * 8 + (Rb1 & 7);
                const u16t* a0h = pih + (size_t)g0 * HID;
                const u16t* a0l = pil + (size_t)g0 * HID;
                const u16t* a1h = pih + (size_t)g1 * HID;
                const u16t* a1l = pil + (size_t)g1 * HID;
                float biasv[2][4];
#pragma unroll
                for (int nt = 0; nt < 2; ++nt)
#pragma unroll
                    for (int j = 0; j < 4; ++j) {
                        int R = gn * 256 + (wid * 2 + nt) * 16 + kg * 4 + j;
                        biasv[nt][j] = bsum[((R >> 3) & 3) * HID + (R >> 5) * 8 + (R & 7)];
                    }
                f32x4 acc[4][2];
#pragma unroll
                for (int mt = 0; mt < 4; ++mt)
#pragma unroll
                    for (int nt = 0; nt < 2; ++nt)
                        acc[mt][nt] = (f32x4){0.f, 0.f, 0.f, 0.f};
                for (int kt = 0; kt < 16; ++kt) {
                    int k0 = kt * 32 + kg * 8;
                    s16x8 ah0 = *(const s16x8*)(a0h + k0), al0 = *(const s16x8*)(a0l + k0);
                    s16x8 ah1 = *(const s16x8*)(a1h + k0), al1 = *(const s16x8*)(a1l + k0);
#pragma unroll
                    for (int mt = 0; mt < 4; ++mt) {
                        const u16t* bth = Bthi + (size_t)(mt * 16 + col) * WP;
                        const u16t* btl = Btlo + (size_t)(mt * 16 + col) * WP;
                        s16x8 bh = *(const s16x8*)(bth + k0), bl = *(const s16x8*)(btl + k0);
                        acc[mt][0] = MFMA16(ah0, bh, acc[mt][0]);
                        acc[mt][0] = MFMA16(ah0, bl, acc[mt][0]);
                        acc[mt][0] = MFMA16(al0, bh, acc[mt][0]);
                        acc[mt][1] = MFMA16(ah1, bh, acc[mt][1]);
                        acc[mt][1] = MFMA16(ah1, bl, acc[mt][1]);
                        acc[mt][1] = MFMA16(al1, bh, acc[mt][1]);
                    }
                }
#pragma unroll
                for (int mt = 0; mt < 4; ++mt)
#pragma unroll
                    for (int nt = 0; nt < 2; ++nt)
#pragma unroll
                        for (int j = 0; j < 4; ++j) {
                            int m = gm * 64 + mt * 16 + col;
                            int R = gn * 256 + (wid * 2 + nt) * 16 + kg * 4 + j;
                            int ugt = R >> 5, rl = R & 31;
                            int lwgt = ((ugt >> 2) << 3) | (bg << 2) | (ugt & 3);
                            st_cohf(xpregion + (size_t)lwgt * 16384 + (size_t)m * 32 + rl,
                                    acc[mt][nt][j] + biasv[nt][j]);
                        }
            }
            __syncthreads();                        // xp sc1 stores drained
            if (tid == 0) st_slot(xpd + ug * 4, c + 1);
            // re-stage Whh1 (pure copy) while others finish
            stage_w((u16t*)(ws + WS_PHH1HI), (u16t*)(ws + WS_PHH1LO), Whi, Wlo, u0, tid);
            if (tid < 64) {
                while (true) {
                    int v = ld_slot(xpd + tid * 4);
                    if (__all(v >= c + 1)) break;
                    __builtin_amdgcn_s_sleep(1);
                }
            }
            __syncthreads();
            // ---- steps ----
            for (int tl = 0; tl < CT; ++tl)
                do_step(c * CT + tl, c, tl, tid, wid, col, kg, b0, u0, ug,
                        Whi, Wlo, Hhi, Hlo, Ps, Cs, hbhi, hblo, slots_self,
                        xp_self, true, nullptr);
        }
    }
}

// =====================================================================
// output projection: reconstruct h_last f32 from hi/lo planes (parity 1)
// =====================================================================
__global__ void outproj_kernel(const char* __restrict__ ws, const float* __restrict__ bout,
                               float* __restrict__ out)
{
    __shared__ float hs[HID];
    int b = blockIdx.x;
    const u16t* hh = (const u16t*)(ws + WS_HB1HI) + (size_t)(BATCH + b) * HID;
    const u16t* hl = (const u16t*)(ws + WS_HB1LO) + (size_t)(BATCH + b) * HID;
    for (int i = threadIdx.x; i < HID; i += 128)
        hs[i] = __uint_as_float((u32t)hh[i] << 16) + __uint_as_float((u32t)hl[i] << 16);
    __syncthreads();
    int o = threadIdx.x;
    const float* Wot = (const float*)(ws + WS_WOT);
    float acc = bout[o];
#pragma unroll 8
    for (int k = 0; k < HID; ++k) acc = fmaf(hs[k], Wot[k * 128 + o], acc);
    out[b * 128 + o] = acc;
}

// =====================================================================
extern "C" void kernel_launch(void* const* d_in, const int* in_sizes, int n_in,
                              void* d_out, int out_size, void* d_ws, size_t ws_size,
                              hipStream_t stream)
{
    (void)in_sizes; (void)n_in; (void)out_size; (void)ws_size;
    const float* prim = (const float*)d_in[0];
    const float* aux  = (const float*)d_in[1];
    const float* Wih0 = (const float*)d_in[2];
    const float* Whh0 = (const float*)d_in[3];
    const float* bih0 = (const float*)d_in[4];
    const float* bhh0 = (const float*)d_in[5];
    const float* Wih1 = (const float*)d_in[6];
    const float* Whh1 = (const float*)d_in[7];
    const float* bih1 = (const float*)d_in[8];
    const float* bhh1 = (const float*)d_in[9];
    const float* Wout = (const float*)d_in[10];
    const float* bout = (const float*)d_in[11];
    float* out = (float*)d_out;
    char* wsc  = (char*)d_ws;

    hipMemsetAsync(wsc, 0, WS_STATE_END, stream);
    prep_kernel<<<4096, 256, 0, stream>>>(Wih0, Whh0, bih0, bhh0,
                                          Wih1, Whh1, bih1, bhh1, Wout, wsc);

    void* margs[] = {(void*)&prim, (void*)&aux, (void*)&wsc};
    hipLaunchCooperativeKernel((void*)mega_kernel, dim3(256), dim3(512), margs, 0, stream);

    outproj_kernel<<<64, 128, 0, stream>>>(wsc, bout, out);
}